// Round 1
// baseline (226.298 us; speedup 1.0000x reference)
//
#include <hip/hip_runtime.h>
#include <hip/hip_bf16.h>

// LSTM cell, B=65536, I=H=128, fp32 I/O. R5: full-gate blocks (32 batch rows x
// all 512 gate cols per block, K=256 staged once) -> zero A re-fetch across
// blocks; A staged as fp32 via global_load_lds DMA (8 KB in flight per wave,
// attacks the Little's-law latency bound), fp32->bf16 convert on LDS read.
// Source-side XOR-octet swizzle (rule #21: linear DMA dest + inverse-swizzled
// source + swizzled ds_read) keeps ds_read_b128 bank-uniform.

typedef short s16x8 __attribute__((ext_vector_type(8)));
typedef float f32x4 __attribute__((ext_vector_type(4)));

__device__ __forceinline__ short f2bf(float f) {
    __hip_bfloat16 h = __float2bfloat16(f);
    return __builtin_bit_cast(short, h);
}
__device__ __forceinline__ float sigm(float x) { return 1.0f / (1.0f + __expf(-x)); }
__device__ __forceinline__ float tanh_f(float x) { return 1.0f - 2.0f / (1.0f + __expf(2.0f * x)); }

__device__ __forceinline__ void dma16(const float* g, void* lds) {
    __builtin_amdgcn_global_load_lds(
        (const __attribute__((address_space(1))) void*)g,
        (__attribute__((address_space(3))) void*)lds, 16, 0, 0);
}

// ---- kernel 1: repack 8 fp32 weight mats -> bf16 MFMA-fragment order ----
// Frag fi = (jt16*4 + g)*8 + ks  (256 frags x 1 KB). Lane l of frag holds
// W[g][j = jt16*16 + (l&15)][k = ks*32 + (l>>4)*8 .. +8), k<128 from W_x,
// k>=128 from W_h (k-128). Element order: v[0..3]=k+0..3, v[4..7]=k+4..7.
__global__ __launch_bounds__(256)
void repack_weights(const float* __restrict__ Wii, const float* __restrict__ Whi,
                    const float* __restrict__ Wif, const float* __restrict__ Whf,
                    const float* __restrict__ Wig, const float* __restrict__ Whg,
                    const float* __restrict__ Wio, const float* __restrict__ Who,
                    short* __restrict__ ws)
{
    const int t   = blockIdx.x * 256 + threadIdx.x;   // 16384 threads
    const int fi  = t >> 6;
    const int l   = t & 63;
    const int ks  = fi & 7;
    const int g   = (fi >> 3) & 3;
    const int jt  = fi >> 5;
    const int j   = jt * 16 + (l & 15);
    const int k   = ks * 32 + (l >> 4) * 8;

    const float* wx = (g == 0) ? Wii : (g == 1) ? Wif : (g == 2) ? Wig : Wio;
    const float* wh = (g == 0) ? Whi : (g == 1) ? Whf : (g == 2) ? Whg : Who;
    const float* src = (k < 128) ? (wx + (size_t)j * 128 + k)
                                 : (wh + (size_t)j * 128 + (k - 128));
    f32x4 a = *(const f32x4*)src;
    f32x4 b = *(const f32x4*)(src + 4);
    s16x8 v;
#pragma unroll
    for (int q = 0; q < 4; ++q) { v[q] = f2bf(a[q]); v[4 + q] = f2bf(b[q]); }
    *(s16x8*)(ws + (size_t)t * 8) = v;
}

// ---- kernel 2: main fused LSTM ----
// Block: 32 batch rows x 512 gate cols (all 4 gates x 128 j). 4 waves, wave w
// owns j in [w*32, w*32+32). LDS: 32 rows x 1 KB; row m = [x_m | h_m] fp32,
// 64 x 16B chunks, chunk p holds global chunk (p&32) | ((p&31) ^ (m&7)).
__global__ __launch_bounds__(256, 4)
void lstm_cell_kernel(const float* __restrict__ X,
                      const float* __restrict__ H,
                      const float* __restrict__ C,
                      const float* __restrict__ Bi, const float* __restrict__ Bf,
                      const float* __restrict__ Bg, const float* __restrict__ Bo,
                      const short* __restrict__ WS,
                      float* __restrict__ OutH,
                      float* __restrict__ OutC)
{
    __shared__ __align__(16) char sA[32768];   // 32 rows x 64 chunks x 16B

    const int tid = threadIdx.x;
    const int l   = tid & 63;
    const int w   = tid >> 6;
    const int lj  = l & 15;
    const int lq  = l >> 4;
    const int B0  = blockIdx.x * 32;

    // ---- stage A: 32 DMA instrs of 1 KB (one LDS row each), 8 per wave ----
    // Lane i of instr for row m: dest = sA + m*1024 + i*16 (linear, HW-fixed);
    // source chunk = (i&31) ^ (m&7) of X-row (i<32) or H-row (i>=32).
    {
        const int  ci   = l & 31;
        const float* base = (l >= 32) ? H : X;
#pragma unroll
        for (int r = 0; r < 8; ++r) {
            const int m = w * 8 + r;                 // m & 7 == r
            const float* src = base + (size_t)(B0 + m) * 128 + ((ci ^ r) << 2);
            dma16(src, (void*)(sA + m * 1024));
        }
    }

    f32x4 acc[2][2][4];   // [mt][jn][g]
#pragma unroll
    for (int mt = 0; mt < 2; ++mt)
#pragma unroll
        for (int jn = 0; jn < 2; ++jn)
#pragma unroll
            for (int g = 0; g < 4; ++g)
                acc[mt][jn][g] = (f32x4){0.f, 0.f, 0.f, 0.f};

    // wave's weight frags: fi = w*64 + jn*32 + g*8 + ks, 1 KB each (L2-resident)
    const short* wsw = WS + (size_t)w * 64 * 512 + l * 8;

    __syncthreads();   // waits vmcnt(0): all DMA landed

    // ---- MFMA: 8 k-steps of 32 over K=256 ( ks<4: x-half, ks>=4: h-half ) ----
#pragma unroll
    for (int ks = 0; ks < 8; ++ks) {
        s16x8 af[2];
#pragma unroll
        for (int mt = 0; mt < 2; ++mt) {
            const int m  = mt * 16 + lj;                  // m & 7 == lj & 7
            const int cg = ks * 8 + lq * 2;               // global chunk (even)
            const int p0 = (cg & 32) | ((cg & 31) ^ (m & 7));
            const f32x4 q0 = *(const f32x4*)(sA + m * 1024 + p0 * 16);
            const f32x4 q1 = *(const f32x4*)(sA + m * 1024 + (p0 ^ 1) * 16);
            s16x8 v;
#pragma unroll
            for (int q = 0; q < 4; ++q) { v[q] = f2bf(q0[q]); v[4 + q] = f2bf(q1[q]); }
            af[mt] = v;
        }
#pragma unroll
        for (int jn = 0; jn < 2; ++jn)
#pragma unroll
            for (int g = 0; g < 4; ++g) {
                const s16x8 bf = *(const s16x8*)(wsw + (size_t)(jn * 32 + g * 8 + ks) * 512);
                acc[0][jn][g] = __builtin_amdgcn_mfma_f32_16x16x32_bf16(af[0], bf, acc[0][jn][g], 0, 0, 0);
                acc[1][jn][g] = __builtin_amdgcn_mfma_f32_16x16x32_bf16(af[1], bf, acc[1][jn][g], 0, 0, 0);
            }
    }

    // ---- epilogue: all 4 gates of (b,j) in this lane; fp32 I/O ----
#pragma unroll
    for (int jn = 0; jn < 2; ++jn) {
        const int j = w * 32 + jn * 16 + lj;
        const float bi  = Bi[j];
        const float bfv = Bf[j];
        const float bg  = Bg[j];
        const float bo  = Bo[j];
#pragma unroll
        for (int mt = 0; mt < 2; ++mt) {
#pragma unroll
            for (int r = 0; r < 4; ++r) {
                const int b = B0 + mt * 16 + lq * 4 + r;   // C/D: row=(lane>>4)*4+reg
                const size_t idx = (size_t)b * 128 + j;
                const float ia = acc[mt][jn][0][r] + bi;
                const float fa = acc[mt][jn][1][r] + bfv;
                const float ga = acc[mt][jn][2][r] + bg;
                const float oa = acc[mt][jn][3][r] + bo;
                const float it = sigm(ia);
                const float ft = sigm(fa);
                const float gt = tanh_f(ga);
                const float ot = sigm(oa);
                const float co = C[idx];
                const float cn = ft * co + it * gt;
                const float hn = ot * tanh_f(cn);
                OutH[idx] = hn;
                OutC[idx] = cn;
            }
        }
    }
}

extern "C" void kernel_launch(void* const* d_in, const int* in_sizes, int n_in,
                              void* d_out, int out_size, void* d_ws, size_t ws_size,
                              hipStream_t stream) {
    const float* X   = (const float*)d_in[0];
    const float* H   = (const float*)d_in[1];
    const float* C   = (const float*)d_in[2];
    const float* Wii = (const float*)d_in[3];
    const float* Whi = (const float*)d_in[4];
    const float* Bi  = (const float*)d_in[5];
    const float* Wif = (const float*)d_in[6];
    const float* Whf = (const float*)d_in[7];
    const float* Bf  = (const float*)d_in[8];
    const float* Wig = (const float*)d_in[9];
    const float* Whg = (const float*)d_in[10];
    const float* Bg  = (const float*)d_in[11];
    const float* Wio = (const float*)d_in[12];
    const float* Who = (const float*)d_in[13];
    const float* Bo  = (const float*)d_in[14];

    short* ws = (short*)d_ws;   // 256 KB bf16 fragment-ordered weights

    hipLaunchKernelGGL(repack_weights, dim3(64), dim3(256), 0, stream,
                       Wii, Whi, Wif, Whf, Wig, Whg, Wio, Who, ws);

    float* OutH = (float*)d_out;
    float* OutC = OutH + (size_t)65536 * 128;

    hipLaunchKernelGGL(lstm_cell_kernel, dim3(2048), dim3(256), 0, stream,
                       X, H, C, Bi, Bf, Bg, Bo, ws, OutH, OutC);
}

// Round 2
// 185.050 us; speedup vs baseline: 1.2229x; 1.2229x over previous
//
#include <hip/hip_runtime.h>
#include <hip/hip_bf16.h>

// LSTM cell, B=65536, I=H=128, fp32 I/O. R6: persistent full-gate blocks.
// 256 blocks x 512 threads (8 waves); block processes 8 tiles of 32 batch
// rows. Wave w owns j-group w (16 j x 4 gates); its 32 weight fragments
// (128 VGPR) load ONCE per block. Double-buffered LDS A-staging via
// global_load_lds DMA, counted-vmcnt pipeline (tile t+2 DMA + C-prefetch
// issued during tile t epilogue; never drain vmcnt to 0 mid-loop).
// Raw s_barrier (NOT __syncthreads -> would drain vmcnt(0)).

typedef short s16x8 __attribute__((ext_vector_type(8)));
typedef float f32x4 __attribute__((ext_vector_type(4)));

__device__ __forceinline__ short f2bf(float f) {
    __hip_bfloat16 h = __float2bfloat16(f);
    return __builtin_bit_cast(short, h);
}
__device__ __forceinline__ float sigm(float x) { return 1.0f / (1.0f + __expf(-x)); }
__device__ __forceinline__ float tanh_f(float x) { return 1.0f - 2.0f / (1.0f + __expf(2.0f * x)); }

__device__ __forceinline__ void dma16(const float* g, void* lds) {
    __builtin_amdgcn_global_load_lds(
        (const __attribute__((address_space(1))) void*)g,
        (__attribute__((address_space(3))) void*)lds, 16, 0, 0);
}

// ---- kernel 1: repack 8 fp32 weight mats -> bf16 MFMA-fragment order ----
// Frag fi = (jt16*4 + g)*8 + ks  (256 frags x 1 KB). Lane l of frag holds
// W[g][j = jt16*16 + (l&15)][k = ks*32 + (l>>4)*8 .. +8), k<128 from W_x,
// k>=128 from W_h (k-128). Element order: v[0..3]=k+0..3, v[4..7]=k+4..7.
__global__ __launch_bounds__(256)
void repack_weights(const float* __restrict__ Wii, const float* __restrict__ Whi,
                    const float* __restrict__ Wif, const float* __restrict__ Whf,
                    const float* __restrict__ Wig, const float* __restrict__ Whg,
                    const float* __restrict__ Wio, const float* __restrict__ Who,
                    short* __restrict__ ws)
{
    const int t   = blockIdx.x * 256 + threadIdx.x;   // 16384 threads
    const int fi  = t >> 6;
    const int l   = t & 63;
    const int ks  = fi & 7;
    const int g   = (fi >> 3) & 3;
    const int jt  = fi >> 5;
    const int j   = jt * 16 + (l & 15);
    const int k   = ks * 32 + (l >> 4) * 8;

    const float* wx = (g == 0) ? Wii : (g == 1) ? Wif : (g == 2) ? Wig : Wio;
    const float* wh = (g == 0) ? Whi : (g == 1) ? Whf : (g == 2) ? Whg : Who;
    const float* src = (k < 128) ? (wx + (size_t)j * 128 + k)
                                 : (wh + (size_t)j * 128 + (k - 128));
    f32x4 a = *(const f32x4*)src;
    f32x4 b = *(const f32x4*)(src + 4);
    s16x8 v;
#pragma unroll
    for (int q = 0; q < 4; ++q) { v[q] = f2bf(a[q]); v[4 + q] = f2bf(b[q]); }
    *(s16x8*)(ws + (size_t)t * 8) = v;
}

// ---- kernel 2: main fused LSTM (persistent, pipelined) ----
// LDS row m (of 32): [x_m | h_m] fp32, 64 x 16B chunks; chunk p holds global
// chunk (p&32) | ((p&31) ^ (m&7))  (source-side swizzle, DMA dest linear).
__global__ __launch_bounds__(512, 2)
void lstm_cell_kernel(const float* __restrict__ X,
                      const float* __restrict__ H,
                      const float* __restrict__ C,
                      const float* __restrict__ Bi, const float* __restrict__ Bf,
                      const float* __restrict__ Bg, const float* __restrict__ Bo,
                      const short* __restrict__ WS,
                      float* __restrict__ OutH,
                      float* __restrict__ OutC)
{
    __shared__ __align__(16) char sA[65536];   // 2 bufs x 32 rows x 1 KB

    const int tid = threadIdx.x;
    const int l   = tid & 63;
    const int w   = tid >> 6;          // 0..7
    const int lj  = l & 15;
    const int lq  = l >> 4;
    const int jw  = w * 16 + lj;       // this lane's j (all 4 gates)
    const int tile0 = blockIdx.x * 8;

    // ---- weights -> registers, once (32 frags = 128 VGPR) ----
    s16x8 wreg[4][8];                  // [g][ks]
    {
        const short* wp = WS + (size_t)(w * 4) * 8 * 512 + l * 8;
#pragma unroll
        for (int g = 0; g < 4; ++g)
#pragma unroll
            for (int ks = 0; ks < 8; ++ks)
                wreg[g][ks] = *(const s16x8*)(wp + (size_t)(g * 8 + ks) * 512);
    }
    const float bi  = Bi[jw];
    const float bfv = Bf[jw];
    const float bg  = Bg[jw];
    const float bo  = Bo[jw];

    // ---- pipeline helpers ----
    const int   ci    = l & 31;
    const float* abase = (l >= 32) ? H : X;

    auto STAGE = [&](int t) {          // 4 DMA x 1 KB: rows w*4..w*4+3
        const int B0 = (tile0 + t) * 32;
        char* dst = sA + (t & 1) * 32768;
#pragma unroll
        for (int r = 0; r < 4; ++r) {
            const int m = w * 4 + r;
            const float* src = abase + (size_t)(B0 + m) * 128 + ((ci ^ (m & 7)) << 2);
            dma16(src, dst + m * 1024);
        }
    };

    float cp[2][8];                    // C prefetch, double-buffered
    auto CLOAD = [&](int t, float* c) {   // 8 scalar loads (coalesced 64B/16 lanes)
        const int B0 = (tile0 + t) * 32;
#pragma unroll
        for (int mt = 0; mt < 2; ++mt)
#pragma unroll
            for (int r = 0; r < 4; ++r)
                c[mt * 4 + r] = C[(size_t)(B0 + mt * 16 + lq * 4 + r) * 128 + jw];
    };

    // ---- prologue: tiles 0 and 1 in flight ----
    STAGE(0);  CLOAD(0, cp[0]);
    STAGE(1);  CLOAD(1, cp[1]);

#pragma unroll 2
    for (int t = 0; t < 8; ++t) {
        // wait own DMA(t)+C(t); keep D(t+1),C(t+1),S(t-1) in flight.
        // issue order/iter: [S(t):16][D(t+2):4][C(t+2):8] (pinned below).
        if (t == 0)      asm volatile("s_waitcnt vmcnt(0)" ::: "memory");
        else if (t == 7) asm volatile("s_waitcnt vmcnt(16)" ::: "memory");
        else             asm volatile("s_waitcnt vmcnt(28)" ::: "memory");
        __builtin_amdgcn_sched_barrier(0);
        __builtin_amdgcn_s_barrier();              // all waves' DMA(t) landed
        __builtin_amdgcn_sched_barrier(0);

        const char* sb = sA + (t & 1) * 32768;

        f32x4 acc[2][4];                           // [mt][g]
#pragma unroll
        for (int mt = 0; mt < 2; ++mt)
#pragma unroll
            for (int g = 0; g < 4; ++g)
                acc[mt][g] = (f32x4){0.f, 0.f, 0.f, 0.f};

#pragma unroll
        for (int ks = 0; ks < 8; ++ks) {
            s16x8 af[2];
#pragma unroll
            for (int mt = 0; mt < 2; ++mt) {
                const int m  = mt * 16 + lj;
                const int cg = ks * 8 + lq * 2;
                const int p0 = (cg & 32) | ((cg & 31) ^ (m & 7));
                const f32x4 q0 = *(const f32x4*)(sb + m * 1024 + p0 * 16);
                const f32x4 q1 = *(const f32x4*)(sb + m * 1024 + (p0 ^ 1) * 16);
                s16x8 v;
#pragma unroll
                for (int q = 0; q < 4; ++q) { v[q] = f2bf(q0[q]); v[4 + q] = f2bf(q1[q]); }
                af[mt] = v;
            }
#pragma unroll
            for (int g = 0; g < 4; ++g) {
                acc[0][g] = __builtin_amdgcn_mfma_f32_16x16x32_bf16(af[0], wreg[g][ks], acc[0][g], 0, 0, 0);
                acc[1][g] = __builtin_amdgcn_mfma_f32_16x16x32_bf16(af[1], wreg[g][ks], acc[1][g], 0, 0, 0);
            }
        }

        __builtin_amdgcn_sched_barrier(0);
        __builtin_amdgcn_s_barrier();              // all waves done reading buf[t&1]
        __builtin_amdgcn_sched_barrier(0);

        // ---- epilogue: 4 gates of (b,j) in-lane; C from prefetch regs ----
        {
            const int B0 = (tile0 + t) * 32;
#pragma unroll
            for (int mt = 0; mt < 2; ++mt) {
#pragma unroll
                for (int r = 0; r < 4; ++r) {
                    const int b = B0 + mt * 16 + lq * 4 + r;
                    const size_t idx = (size_t)b * 128 + jw;
                    const float ia = acc[mt][0][r] + bi;
                    const float fa = acc[mt][1][r] + bfv;
                    const float ga = acc[mt][2][r] + bg;
                    const float oa = acc[mt][3][r] + bo;
                    const float it = sigm(ia);
                    const float ft = sigm(fa);
                    const float gt = tanh_f(ga);
                    const float ot = sigm(oa);
                    const float co = cp[t & 1][mt * 4 + r];
                    const float cn = ft * co + it * gt;
                    const float hn = ot * tanh_f(cn);
                    OutH[idx] = hn;
                    OutC[idx] = cn;
                }
            }
        }

        __builtin_amdgcn_sched_barrier(0);
        if (t < 6) {                               // issue tile t+2
            STAGE(t + 2);
            CLOAD(t + 2, cp[t & 1]);               // slot t&1 just consumed
        }
        __builtin_amdgcn_sched_barrier(0);
    }
}

extern "C" void kernel_launch(void* const* d_in, const int* in_sizes, int n_in,
                              void* d_out, int out_size, void* d_ws, size_t ws_size,
                              hipStream_t stream) {
    const float* X   = (const float*)d_in[0];
    const float* H   = (const float*)d_in[1];
    const float* C   = (const float*)d_in[2];
    const float* Wii = (const float*)d_in[3];
    const float* Whi = (const float*)d_in[4];
    const float* Bi  = (const float*)d_in[5];
    const float* Wif = (const float*)d_in[6];
    const float* Whf = (const float*)d_in[7];
    const float* Bf  = (const float*)d_in[8];
    const float* Wig = (const float*)d_in[9];
    const float* Whg = (const float*)d_in[10];
    const float* Bg  = (const float*)d_in[11];
    const float* Wio = (const float*)d_in[12];
    const float* Who = (const float*)d_in[13];
    const float* Bo  = (const float*)d_in[14];

    short* ws = (short*)d_ws;   // 256 KB bf16 fragment-ordered weights

    hipLaunchKernelGGL(repack_weights, dim3(64), dim3(256), 0, stream,
                       Wii, Whi, Wif, Whf, Wig, Whg, Wio, Who, ws);

    float* OutH = (float*)d_out;
    float* OutC = OutH + (size_t)65536 * 128;

    hipLaunchKernelGGL(lstm_cell_kernel, dim3(256), dim3(512), 0, stream,
                       X, H, C, Bi, Bf, Bg, Bo, ws, OutH, OutC);
}